// Round 5
// baseline (33.521 us; speedup 1.0000x reference)
//
#include <hip/hip_runtime.h>
#include <math.h>

#define S_ 8
#define J_ 4
#define D_ 4
#define P_ 3
#define N_ 1024
#define BG_ 32
#define BU_ 32
#define MG_ 10
#define MU_ 32

static constexpr float PI_F = 3.14159265358979323846f;

// workspace float offsets
#define COEF_OFF   0        // [s][j][bu][d][2]  = 8192
#define C1_OFF     8192     // [d][p][b][s]      = 3072
#define C2_OFF     11264    // [d][p][b][s]      = 3072
#define SQG_OFF    14336    // [d][p][g][s]      = 960
#define QUAMP_OFF  15296    // [d][s][m]         = 1024

// ================= prep: coef + tables (168 blocks x 128) ====================
__global__ __launch_bounds__(128) void prep_kernel(
    const float* __restrict__ alphas, const float* __restrict__ pgs,
    const float* __restrict__ zgs,    const float* __restrict__ thetag,
    const float* __restrict__ betag,  const float* __restrict__ wg,
    const float* __restrict__ qg,     const float* __restrict__ pus,
    const float* __restrict__ thetau, const float* __restrict__ betau,
    const float* __restrict__ wu,     const float* __restrict__ qu,
    const float* __restrict__ ampu_p, const float* __restrict__ log_amps,
    float* __restrict__ ws)
{
    int tid = blockIdx.x * 128 + threadIdx.x;
    float ampu = ampu_p[0];

    if (tid < 16384) {                       // coef, 4-lane split over (b,g)
        int q  = tid & 3;
        int bu = (tid >> 2) & 31;
        int d  = (tid >> 7) & 3;
        int j  = (tid >> 9) & 3;
        int s  = tid >> 11;
        float G3r = 1.f, G3i = 0.f;
        #pragma unroll 1
        for (int p = 0; p < P_; ++p) {
            float alpha = alphas[d*P_ + p], pg = pgs[d*P_ + p];
            float om    = thetau[((s*J_ + j)*P_ + p)*BU_ + bu];
            float inv4a = 0.25f / alpha;
            float pref  = 0.5f * sqrtf(PI_F / alpha);
            float gr = 0.f, gi = 0.f;
            int b0 = q * 8;
            #pragma unroll 2
            for (int bb = 0; bb < 8; ++bb) {
                int b = b0 + bb;
                float th = thetag[(d*P_ + p)*BG_ + b];
                float dm = th - om, dpl = th + om;
                float e1 = __expf(-dm*dm*inv4a);
                float e2 = __expf(-dpl*dpl*inv4a);
                float be = betag[((s*D_ + d)*P_ + p)*BG_ + b];
                float w  = wg   [((s*D_ + d)*P_ + p)*BG_ + b];
                float sb, cb; __sincosf(be, &sb, &cb);
                gr += pref * w * (e1 + e2) * cb;
                gi += pref * w * (e1 - e2) * sb;
            }
            float A = alpha + pg, invA = 1.f / A;
            float decay = __expf(-om*om*0.25f*invA);
            float cc    = sqrtf(PI_F * invA);
            float cr = 0.f, ci = 0.f;
            int g0 = q * 3, gn = (q < 3) ? 3 : 1;
            #pragma unroll 1
            for (int gg = 0; gg < gn; ++gg) {
                int g = g0 + gg;
                float z  = zgs[g*P_ + p];
                float mu = pg * z * invA;
                float rg = alpha * pg * z * z * invA;
                float cg = cc * __expf(-rg);
                float qv = qg[((s*D_ + d)*P_ + p)*MG_ + g];
                float sm, cm; __sincosf(om * mu, &sm, &cm);
                cr += qv * cg * cm;
                ci -= qv * cg * sm;
            }
            #pragma unroll
            for (int off = 1; off < 4; off <<= 1) {
                gr += __shfl_xor(gr, off, 4);
                gi += __shfl_xor(gi, off, 4);
                cr += __shfl_xor(cr, off, 4);
                ci += __shfl_xor(ci, off, 4);
            }
            float Gr = gr + decay * cr;
            float Gi = gi + decay * ci;
            float nr = G3r*Gr - G3i*Gi;
            float ni = G3r*Gi + G3i*Gr;
            G3r = nr; G3i = ni;
        }
        if (q == 0) {
            float bv = betau[(s*J_ + j)*BU_ + bu];
            float wv = wu   [(s*J_ + j)*BU_ + bu];
            float sbu, cbu; __sincosf(bv, &sbu, &cbu);
            float cuR = wv * cbu, cuI = wv * sbu;
            float amp = ampu * __expf(log_amps[d*J_ + j]);
            int base = (((s*J_ + j)*BU_ + bu)*D_ + d) * 2;
            ws[COEF_OFF + base    ] = amp * (cuR*G3r - cuI*G3i);
            ws[COEF_OFF + base + 1] = amp * (cuR*G3i + cuI*G3r);
        }
    } else if (tid < 16384 + 3072) {         // c1/c2: [d][p][b][s]
        int id = tid - 16384;
        int s = id & 7, b = (id >> 3) & 31, dp = id >> 8;
        int d = dp / P_, p = dp % P_;
        float alpha = alphas[d*P_ + p];
        float Bm = alpha + pus[p];
        float th = thetag[dp*BG_ + b];
        float spec = sqrtf(PI_F / Bm) * __expf(-th*th*0.25f/Bm);
        float be = betag[((s*D_ + d)*P_ + p)*BG_ + b];
        float w  = wg   [((s*D_ + d)*P_ + p)*BG_ + b];
        float sb, cb; __sincosf(be, &sb, &cb);
        ws[C1_OFF + id] = w * cb * spec;
        ws[C2_OFF + id] = w * sb * spec;
    } else if (tid < 16384 + 3072 + 960) {   // sqg: [d][p][g][s]
        int id = tid - (16384 + 3072);
        int s = id & 7, g = (id >> 3) % MG_, dp = (id >> 3) / MG_;
        int d = dp / P_, p = dp % P_;
        ws[SQG_OFF + id] = qg[((s*D_ + d)*P_ + p)*MG_ + g];
    } else if (tid < 16384 + 3072 + 960 + 1024) {  // quamp: [d][s][m]
        int id = tid - (16384 + 3072 + 960);
        int m = id & 31, s = (id >> 5) & 7, d = id >> 8;
        float acc = 0.f;
        #pragma unroll
        for (int j = 0; j < J_; ++j)
            acc += __expf(log_amps[d*J_ + j]) * qu[(s*J_ + j)*MU_ + m];
        ws[QUAMP_OFF + id] = ampu * acc;
    }
}

// ===== mega: can-phase (scalar-cached tables) + final phase, one block = 2n ==
// 256 threads.  can:  t = d*64 + nl*32 + m   (wave = one d  -> uniform tables)
//               final:t = fnl*128 + s*16 + k
__global__ __launch_bounds__(256) void mega_kernel(
    const float* __restrict__ ts,     const float* __restrict__ alphas,
    const float* __restrict__ pgs,    const float* __restrict__ zgs,
    const float* __restrict__ thetag, const float* __restrict__ pus,
    const float* __restrict__ zus,    const float* __restrict__ thetau,
    const float* __restrict__ W,
    const float* __restrict__ tabC1,  const float* __restrict__ tabC2,
    const float* __restrict__ tabQG,  const float* __restrict__ tabQA,
    const float* __restrict__ tabCF,
    float* __restrict__ out)
{
    __shared__ float scanpart[2][S_][D_];

    int t  = threadIdx.x;
    int n0 = blockIdx.x * 2;

    // ---------------- can phase ----------------
    {
        int d  = __builtin_amdgcn_readfirstlane(t >> 6);   // wave-uniform SGPR
        int nl = (t >> 5) & 1;
        int m  = t & 31;
        int n  = n0 + nl;

        float zu0 = zus[m*P_ + 0];
        float zu1 = zus[m*P_ + 1];
        float zu2 = zus[m*P_ + 2];
        float zup[P_] = {zu0, zu1, zu2};

        float pr0=1.f,pr1=1.f,pr2=1.f,pr3=1.f,pr4=1.f,pr5=1.f,pr6=1.f,pr7=1.f;

        #pragma unroll 1
        for (int p = 0; p < P_; ++p) {
            float alpha = alphas[d*P_ + p], pg = pgs[d*P_ + p], pu = pus[p];
            float Bm = alpha + pu, invB = 1.f / Bm;
            float kmp = pu * invB;
            float krp = alpha * pu * invB;
            float Cm = Bm + pg, invC = 1.f / Cm;
            float ksc = sqrtf(PI_F * invC);
            float kbc = Bm * pg * invC;

            float c  = ts[n*P_ + p] - zup[p];
            float mp = kmp * c;
            float E  = __expf(-krp * c * c);

            float a0=0.f,a1=0.f,a2=0.f,a3=0.f,a4=0.f,a5=0.f,a6=0.f,a7=0.f;

            const float* tg  = thetag + (d*P_ + p)*BG_;
            const float* c1b = tabC1 + (d*P_ + p)*BG_*S_;
            const float* c2b = tabC2 + (d*P_ + p)*BG_*S_;
            #pragma unroll 4
            for (int b = 0; b < BG_; ++b) {
                float sx, cx; __sincosf(tg[b] * mp, &sx, &cx);
                float nsx = -sx;
                const float* c1 = c1b + b*S_;   // wave-uniform -> s_load
                const float* c2 = c2b + b*S_;
                a0 += c1[0]*cx + c2[0]*nsx;  a1 += c1[1]*cx + c2[1]*nsx;
                a2 += c1[2]*cx + c2[2]*nsx;  a3 += c1[3]*cx + c2[3]*nsx;
                a4 += c1[4]*cx + c2[4]*nsx;  a5 += c1[5]*cx + c2[5]*nsx;
                a6 += c1[6]*cx + c2[6]*nsx;  a7 += c1[7]*cx + c2[7]*nsx;
            }

            const float* qgb = tabQG + (d*P_ + p)*MG_*S_;
            #pragma unroll 2
            for (int g = 0; g < MG_; ++g) {
                float diff = mp - zgs[g*P_ + p];
                float v = ksc * __expf(-kbc*diff*diff);
                const float* qv = qgb + g*S_;   // wave-uniform -> s_load
                a0 += qv[0]*v; a1 += qv[1]*v; a2 += qv[2]*v; a3 += qv[3]*v;
                a4 += qv[4]*v; a5 += qv[5]*v; a6 += qv[6]*v; a7 += qv[7]*v;
            }

            pr0 *= E*a0; pr1 *= E*a1; pr2 *= E*a2; pr3 *= E*a3;
            pr4 *= E*a4; pr5 *= E*a5; pr6 *= E*a6; pr7 *= E*a7;
        }

        float prod[S_] = {pr0,pr1,pr2,pr3,pr4,pr5,pr6,pr7};
        const float* qa = tabQA + d*S_*MU_;
        #pragma unroll
        for (int s = 0; s < S_; ++s) {
            float val = qa[s*MU_ + m] * prod[s];
            #pragma unroll
            for (int off = 16; off; off >>= 1) val += __shfl_xor(val, off, 32);
            if (m == 0) scanpart[nl][s][d] = val;
        }
    }
    __syncthreads();

    // ---------------- final phase ----------------
    {
        int k   = t & 15;
        int s   = (t >> 4) & 7;
        int fnl = t >> 7;
        int n   = n0 + fnl;

        float t0 = ts[n*P_], t1 = ts[n*P_ + 1], t2 = ts[n*P_ + 2];

        float r0=0.f, r1=0.f, r2=0.f, r3=0.f;
        #pragma unroll 2
        for (int i = 0; i < 8; ++i) {
            int j  = i >> 1;
            int bu = (i & 1) * 16 + k;
            const float* thp = thetau + ((s*J_ + j)*P_)*BU_ + bu;
            float phi = thp[0]*t0 + thp[BU_]*t1 + thp[2*BU_]*t2;
            float sp, cp; __sincosf(phi, &sp, &cp);
            const float4* cf = (const float4*)(tabCF + ((s*J_ + j)*BU_ + bu)*8);
            float4 u = cf[0], v = cf[1];
            r0 += u.x*cp - u.y*sp;
            r1 += u.z*cp - u.w*sp;
            r2 += v.x*cp - v.y*sp;
            r3 += v.z*cp - v.w*sp;
        }
        #pragma unroll
        for (int off = 8; off; off >>= 1) {
            r0 += __shfl_xor(r0, off, 16);
            r1 += __shfl_xor(r1, off, 16);
            r2 += __shfl_xor(r2, off, 16);
            r3 += __shfl_xor(r3, off, 16);
        }
        if (k == 0) {
            float w0 = t0*W[0*D_+0] + t1*W[1*D_+0] + t2*W[2*D_+0];
            float w1 = t0*W[0*D_+1] + t1*W[1*D_+1] + t2*W[2*D_+1];
            float w2 = t0*W[0*D_+2] + t1*W[1*D_+2] + t2*W[2*D_+2];
            float w3 = t0*W[0*D_+3] + t1*W[1*D_+3] + t2*W[2*D_+3];
            float4 o;
            o.x = scanpart[fnl][s][0] + r0 + w0;
            o.y = scanpart[fnl][s][1] + r1 + w1;
            o.z = scanpart[fnl][s][2] + r2 + w2;
            o.w = scanpart[fnl][s][3] + r3 + w3;
            *(float4*)(out + (s*N_ + n)*D_) = o;
        }
    }
}

extern "C" void kernel_launch(void* const* d_in, const int* in_sizes, int n_in,
                              void* d_out, int out_size, void* d_ws, size_t ws_size,
                              hipStream_t stream)
{
    const float* ts       = (const float*)d_in[0];
    const float* alphas   = (const float*)d_in[1];
    const float* pgs      = (const float*)d_in[2];
    const float* zgs      = (const float*)d_in[3];
    const float* thetag   = (const float*)d_in[4];
    const float* betag    = (const float*)d_in[5];
    const float* wg       = (const float*)d_in[6];
    const float* qg       = (const float*)d_in[7];
    const float* pus      = (const float*)d_in[8];
    const float* zus      = (const float*)d_in[9];
    const float* thetau   = (const float*)d_in[10];
    const float* betau    = (const float*)d_in[11];
    const float* wu       = (const float*)d_in[12];
    const float* qu       = (const float*)d_in[13];
    const float* ampu     = (const float*)d_in[14];
    const float* log_amps = (const float*)d_in[15];
    const float* W        = (const float*)d_in[16];
    float* ws  = (float*)d_ws;
    float* out = (float*)d_out;

    prep_kernel<<<168, 128, 0, stream>>>(alphas, pgs, zgs, thetag, betag, wg, qg,
                                         pus, thetau, betau, wu, qu, ampu,
                                         log_amps, ws);
    mega_kernel<<<512, 256, 0, stream>>>(ts, alphas, pgs, zgs, thetag, pus, zus,
                                         thetau, W,
                                         ws + C1_OFF, ws + C2_OFF,
                                         ws + SQG_OFF, ws + QUAMP_OFF,
                                         ws + COEF_OFF, out);
}

// Round 6
// 32.965 us; speedup vs baseline: 1.0169x; 1.0169x over previous
//
#include <hip/hip_runtime.h>
#include <math.h>

#define S_ 8
#define J_ 4
#define D_ 4
#define P_ 3
#define N_ 1024
#define BG_ 32
#define BU_ 32
#define MG_ 10
#define MU_ 32

static constexpr float PI_F = 3.14159265358979323846f;

// workspace float offsets
#define COEF_OFF   0        // [s][j][bu][8]     = 8192
#define C1_OFF     8192     // [d][p][b][s]      = 3072
#define C2_OFF     11264    // [d][p][b][s]      = 3072
#define SQG_OFF    14336    // [d][p][g][s]      = 960
#define QUAMP_OFF  15296    // [d][s][m]         = 1024

// ================= prep: coef + tables (168 blocks x 128) ====================
__global__ __launch_bounds__(128) void prep_kernel(
    const float* __restrict__ alphas, const float* __restrict__ pgs,
    const float* __restrict__ zgs,    const float* __restrict__ thetag,
    const float* __restrict__ betag,  const float* __restrict__ wg,
    const float* __restrict__ qg,     const float* __restrict__ pus,
    const float* __restrict__ thetau, const float* __restrict__ betau,
    const float* __restrict__ wu,     const float* __restrict__ qu,
    const float* __restrict__ ampu_p, const float* __restrict__ log_amps,
    float* __restrict__ ws)
{
    int tid = blockIdx.x * 128 + threadIdx.x;
    float ampu = ampu_p[0];

    if (tid < 16384) {                       // coef, 4-lane split over (b,g)
        int q  = tid & 3;
        int bu = (tid >> 2) & 31;
        int d  = (tid >> 7) & 3;
        int j  = (tid >> 9) & 3;
        int s  = tid >> 11;
        float G3r = 1.f, G3i = 0.f;
        #pragma unroll 1
        for (int p = 0; p < P_; ++p) {
            float alpha = alphas[d*P_ + p], pg = pgs[d*P_ + p];
            float om    = thetau[((s*J_ + j)*P_ + p)*BU_ + bu];
            float inv4a = 0.25f / alpha;
            float pref  = 0.5f * sqrtf(PI_F / alpha);
            float gr = 0.f, gi = 0.f;
            int b0 = q * 8;
            #pragma unroll 2
            for (int bb = 0; bb < 8; ++bb) {
                int b = b0 + bb;
                float th = thetag[(d*P_ + p)*BG_ + b];
                float dm = th - om, dpl = th + om;
                float e1 = __expf(-dm*dm*inv4a);
                float e2 = __expf(-dpl*dpl*inv4a);
                float be = betag[((s*D_ + d)*P_ + p)*BG_ + b];
                float w  = wg   [((s*D_ + d)*P_ + p)*BG_ + b];
                float sb, cb; __sincosf(be, &sb, &cb);
                gr += pref * w * (e1 + e2) * cb;
                gi += pref * w * (e1 - e2) * sb;
            }
            float A = alpha + pg, invA = 1.f / A;
            float decay = __expf(-om*om*0.25f*invA);
            float cc    = sqrtf(PI_F * invA);
            float cr = 0.f, ci = 0.f;
            int g0 = q * 3, gn = (q < 3) ? 3 : 1;
            #pragma unroll 1
            for (int gg = 0; gg < gn; ++gg) {
                int g = g0 + gg;
                float z  = zgs[g*P_ + p];
                float mu = pg * z * invA;
                float rg = alpha * pg * z * z * invA;
                float cg = cc * __expf(-rg);
                float qv = qg[((s*D_ + d)*P_ + p)*MG_ + g];
                float sm, cm; __sincosf(om * mu, &sm, &cm);
                cr += qv * cg * cm;
                ci -= qv * cg * sm;
            }
            #pragma unroll
            for (int off = 1; off < 4; off <<= 1) {
                gr += __shfl_xor(gr, off, 4);
                gi += __shfl_xor(gi, off, 4);
                cr += __shfl_xor(cr, off, 4);
                ci += __shfl_xor(ci, off, 4);
            }
            float Gr = gr + decay * cr;
            float Gi = gi + decay * ci;
            float nr = G3r*Gr - G3i*Gi;
            float ni = G3r*Gi + G3i*Gr;
            G3r = nr; G3i = ni;
        }
        if (q == 0) {
            float bv = betau[(s*J_ + j)*BU_ + bu];
            float wv = wu   [(s*J_ + j)*BU_ + bu];
            float sbu, cbu; __sincosf(bv, &sbu, &cbu);
            float cuR = wv * cbu, cuI = wv * sbu;
            float amp = ampu * __expf(log_amps[d*J_ + j]);
            int base = (((s*J_ + j)*BU_ + bu)*D_ + d) * 2;
            ws[COEF_OFF + base    ] = amp * (cuR*G3r - cuI*G3i);
            ws[COEF_OFF + base + 1] = amp * (cuR*G3i + cuI*G3r);
        }
    } else if (tid < 16384 + 3072) {         // c1/c2: [d][p][b][s]
        int id = tid - 16384;
        int s = id & 7, b = (id >> 3) & 31, dp = id >> 8;
        int d = dp / P_, p = dp % P_;
        float alpha = alphas[d*P_ + p];
        float Bm = alpha + pus[p];
        float th = thetag[dp*BG_ + b];
        float spec = sqrtf(PI_F / Bm) * __expf(-th*th*0.25f/Bm);
        float be = betag[((s*D_ + d)*P_ + p)*BG_ + b];
        float w  = wg   [((s*D_ + d)*P_ + p)*BG_ + b];
        float sb, cb; __sincosf(be, &sb, &cb);
        ws[C1_OFF + id] = w * cb * spec;
        ws[C2_OFF + id] = w * sb * spec;
    } else if (tid < 16384 + 3072 + 960) {   // sqg: [d][p][g][s]
        int id = tid - (16384 + 3072);
        int s = id & 7, g = (id >> 3) % MG_, dp = (id >> 3) / MG_;
        int d = dp / P_, p = dp % P_;
        ws[SQG_OFF + id] = qg[((s*D_ + d)*P_ + p)*MG_ + g];
    } else if (tid < 16384 + 3072 + 960 + 1024) {  // quamp: [d][s][m]
        int id = tid - (16384 + 3072 + 960);
        int m = id & 31, s = (id >> 5) & 7, d = id >> 8;
        float acc = 0.f;
        #pragma unroll
        for (int j = 0; j < J_; ++j)
            acc += __expf(log_amps[d*J_ + j]) * qu[(s*J_ + j)*MU_ + m];
        ws[QUAMP_OFF + id] = ampu * acc;
    }
}

// ====== mega: can phase (LDS tables) + fused final phase; 1 n per block ======
// 256 threads.  can:   t = d*64 + q*32 + m   (q splits b/g; also splits s-reduce)
//               final: t = s*32 + k          (k splits 128 (j,bu) pairs, 4 each)
__global__ __launch_bounds__(256, 4) void mega_kernel(
    const float* __restrict__ ts,     const float* __restrict__ alphas,
    const float* __restrict__ pgs,    const float* __restrict__ zgs,
    const float* __restrict__ thetag, const float* __restrict__ pus,
    const float* __restrict__ zus,    const float* __restrict__ thetau,
    const float* __restrict__ W,      const float* __restrict__ ws,
    float* __restrict__ out)
{
    __shared__ float sc1[D_][P_][BG_][S_];   // 3072
    __shared__ float sc2[D_][P_][BG_][S_];   // 3072
    __shared__ float sqg[D_][P_][MG_][S_];   // 960
    __shared__ float squ[D_][S_][MU_];       // 1024
    __shared__ float stg[D_][P_][BG_];       // 384
    __shared__ float szg[P_][MG_];           // 30
    __shared__ float szu[P_][MU_];           // 96
    __shared__ float scan[S_][D_];           // 32

    int t = threadIdx.x;
    int n = blockIdx.x;

    // ---- stage tables (vector-friendly, layouts match ws exactly) ----
    for (int i = t; i < P_*BG_*S_*D_; i += 256) {
        ((float*)sc1)[i] = ws[C1_OFF + i];
        ((float*)sc2)[i] = ws[C2_OFF + i];
    }
    for (int i = t; i < D_*P_*MG_*S_; i += 256) ((float*)sqg)[i] = ws[SQG_OFF + i];
    for (int i = t; i < D_*S_*MU_; i += 256)    ((float*)squ)[i] = ws[QUAMP_OFF + i];
    for (int i = t; i < D_*P_*BG_; i += 256)    ((float*)stg)[i] = thetag[i];
    if (t < P_*MG_) { int p = t / MG_, g = t % MG_; szg[p][g] = zgs[g*P_ + p]; }
    if (t >= 64 && t < 64 + P_*MU_) {
        int i = t - 64; int p = i >> 5, m = i & 31;
        szu[p][m] = zus[m*P_ + p];
    }
    __syncthreads();

    float t0 = ts[n*P_], t1 = ts[n*P_ + 1], t2 = ts[n*P_ + 2];

    // -------------------- can phase --------------------
    {
        int m = t & 31, q = (t >> 5) & 1, d = t >> 6;
        float tsn[P_] = {t0, t1, t2};

        float pr0=1.f,pr1=1.f,pr2=1.f,pr3=1.f,pr4=1.f,pr5=1.f,pr6=1.f,pr7=1.f;

        #pragma unroll 1
        for (int p = 0; p < P_; ++p) {
            float alpha = alphas[d*P_ + p], pg = pgs[d*P_ + p], pu = pus[p];
            float Bm = alpha + pu, invB = 1.f / Bm;
            float kmp = pu * invB;
            float krp = alpha * pu * invB;
            float Cm = Bm + pg, invC = 1.f / Cm;
            float ksc = sqrtf(PI_F * invC);
            float kbc = Bm * pg * invC;

            float c  = tsn[p] - szu[p][m];
            float mp = kmp * c;
            float E  = __expf(-krp * c * c);

            float a0=0.f,a1=0.f,a2=0.f,a3=0.f,a4=0.f,a5=0.f,a6=0.f,a7=0.f;
            int b0 = q * 16;
            #pragma unroll 4
            for (int bb = 0; bb < 16; ++bb) {
                int b = b0 + bb;
                float sx, cx; __sincosf(stg[d][p][b] * mp, &sx, &cx);
                const float4* c1v = (const float4*)&sc1[d][p][b][0];
                const float4* c2v = (const float4*)&sc2[d][p][b][0];
                float4 u0 = c1v[0], u1 = c1v[1];
                float4 v0 = c2v[0], v1 = c2v[1];
                a0 += u0.x*cx - v0.x*sx;  a1 += u0.y*cx - v0.y*sx;
                a2 += u0.z*cx - v0.z*sx;  a3 += u0.w*cx - v0.w*sx;
                a4 += u1.x*cx - v1.x*sx;  a5 += u1.y*cx - v1.y*sx;
                a6 += u1.z*cx - v1.z*sx;  a7 += u1.w*cx - v1.w*sx;
            }
            int g0 = q * 5;
            #pragma unroll 1
            for (int gg = 0; gg < 5; ++gg) {
                int g = g0 + gg;
                float diff = mp - szg[p][g];
                float v = ksc * __expf(-kbc*diff*diff);
                const float4* qv = (const float4*)&sqg[d][p][g][0];
                float4 q0 = qv[0], q1 = qv[1];
                a0 += q0.x*v; a1 += q0.y*v; a2 += q0.z*v; a3 += q0.w*v;
                a4 += q1.x*v; a5 += q1.y*v; a6 += q1.z*v; a7 += q1.w*v;
            }
            // combine q-halves (partner = lane ^ 32 within the wave)
            a0 += __shfl_xor(a0, 32, 64); a1 += __shfl_xor(a1, 32, 64);
            a2 += __shfl_xor(a2, 32, 64); a3 += __shfl_xor(a3, 32, 64);
            a4 += __shfl_xor(a4, 32, 64); a5 += __shfl_xor(a5, 32, 64);
            a6 += __shfl_xor(a6, 32, 64); a7 += __shfl_xor(a7, 32, 64);
            pr0 *= E*a0; pr1 *= E*a1; pr2 *= E*a2; pr3 *= E*a3;
            pr4 *= E*a4; pr5 *= E*a5; pr6 *= E*a6; pr7 *= E*a7;
        }

        // s-reduce: q=0 handles s=0..3, q=1 handles s=4..7 (both hold full sums)
        float prod[S_] = {pr0,pr1,pr2,pr3,pr4,pr5,pr6,pr7};
        int s0 = q * 4;
        #pragma unroll
        for (int ss = 0; ss < 4; ++ss) {
            int s = s0 + ss;
            float val = squ[d][s][m] * prod[s];
            #pragma unroll
            for (int off = 16; off; off >>= 1) val += __shfl_xor(val, off, 32);
            if (m == 0) scan[s][d] = val;
        }
    }
    __syncthreads();

    // -------------------- final phase --------------------
    {
        int k = t & 31;
        int s = t >> 5;

        float r0=0.f, r1=0.f, r2=0.f, r3=0.f;
        #pragma unroll 2
        for (int j = 0; j < J_; ++j) {
            const float* thp = thetau + ((s*J_ + j)*P_)*BU_ + k;
            float phi = thp[0]*t0 + thp[BU_]*t1 + thp[2*BU_]*t2;
            float sp, cp; __sincosf(phi, &sp, &cp);
            const float4* cf = (const float4*)(ws + COEF_OFF + ((s*J_ + j)*BU_ + k)*8);
            float4 u = cf[0], v = cf[1];
            r0 += u.x*cp - u.y*sp;
            r1 += u.z*cp - u.w*sp;
            r2 += v.x*cp - v.y*sp;
            r3 += v.z*cp - v.w*sp;
        }
        #pragma unroll
        for (int off = 16; off; off >>= 1) {
            r0 += __shfl_xor(r0, off, 32);
            r1 += __shfl_xor(r1, off, 32);
            r2 += __shfl_xor(r2, off, 32);
            r3 += __shfl_xor(r3, off, 32);
        }
        if (k == 0) {
            float4 o;
            o.x = scan[s][0] + r0 + t0*W[0*D_+0] + t1*W[1*D_+0] + t2*W[2*D_+0];
            o.y = scan[s][1] + r1 + t0*W[0*D_+1] + t1*W[1*D_+1] + t2*W[2*D_+1];
            o.z = scan[s][2] + r2 + t0*W[0*D_+2] + t1*W[1*D_+2] + t2*W[2*D_+2];
            o.w = scan[s][3] + r3 + t0*W[0*D_+3] + t1*W[1*D_+3] + t2*W[2*D_+3];
            *(float4*)(out + (s*N_ + n)*D_) = o;
        }
    }
}

extern "C" void kernel_launch(void* const* d_in, const int* in_sizes, int n_in,
                              void* d_out, int out_size, void* d_ws, size_t ws_size,
                              hipStream_t stream)
{
    const float* ts       = (const float*)d_in[0];
    const float* alphas   = (const float*)d_in[1];
    const float* pgs      = (const float*)d_in[2];
    const float* zgs      = (const float*)d_in[3];
    const float* thetag   = (const float*)d_in[4];
    const float* betag    = (const float*)d_in[5];
    const float* wg       = (const float*)d_in[6];
    const float* qg       = (const float*)d_in[7];
    const float* pus      = (const float*)d_in[8];
    const float* zus      = (const float*)d_in[9];
    const float* thetau   = (const float*)d_in[10];
    const float* betau    = (const float*)d_in[11];
    const float* wu       = (const float*)d_in[12];
    const float* qu       = (const float*)d_in[13];
    const float* ampu     = (const float*)d_in[14];
    const float* log_amps = (const float*)d_in[15];
    const float* W        = (const float*)d_in[16];
    float* ws  = (float*)d_ws;
    float* out = (float*)d_out;

    prep_kernel<<<168, 128, 0, stream>>>(alphas, pgs, zgs, thetag, betag, wg, qg,
                                         pus, thetau, betau, wu, qu, ampu,
                                         log_amps, ws);
    mega_kernel<<<N_, 256, 0, stream>>>(ts, alphas, pgs, zgs, thetag, pus, zus,
                                        thetau, W, ws, out);
}